// Round 27
// baseline (666.374 us; speedup 1.0000x reference)
//
#include <hip/hip_runtime.h>
#include <hip/hip_bf16.h>

#define B_ 256
#define T_ 200
#define D_ 256
#define H_ 4
#define BT_ (B_*T_)
#define DD_ (D_*D_)
#define GS_ 72     // gemm LDS stride (64 + 8 pad)
#define TP_ 208    // padded token rows per batch for qbf/kbf
#define VTP_ 224   // vtbf row length (7*32)
#define ZS_ 264    // cov Zb stride
#define FS_ 264    // ffn Alds/Tlds stride (256 + 8)
#define VS_ 136    // epilogue LDS transpose stride (128 + 8)

typedef __attribute__((ext_vector_type(4))) float  f32x4;
typedef __attribute__((ext_vector_type(8))) __bf16 bf16x8;
typedef __attribute__((ext_vector_type(4))) int    i32x4;
typedef __attribute__((ext_vector_type(2))) int    i32x2;

union frag8 { unsigned u[4]; bf16x8 v; };

__device__ __forceinline__ unsigned short f2bf(float f) {
    unsigned u = __float_as_uint(f);
    u += 0x7FFFu + ((u >> 16) & 1u);          // RNE to bf16
    return (unsigned short)(u >> 16);
}
__device__ __forceinline__ unsigned pk2(float lo, float hi) {
    return (unsigned)f2bf(lo) | ((unsigned)f2bf(hi) << 16);
}
__device__ __forceinline__ float bflo(unsigned u) { return __uint_as_float(u << 16); }
__device__ __forceinline__ float bfhi(unsigned u) { return __uint_as_float(u & 0xFFFF0000u); }

__device__ __forceinline__ float wave_sum(float v) {
#pragma unroll
    for (int o = 32; o >= 1; o >>= 1) v += __shfl_xor(v, o);
    return v;
}

// ---------------- embed (bf16 out) ----------------
__global__ void embed_kernel(const int* __restrict__ ls,
                             const float* __restrict__ itab,
                             const float* __restrict__ ptab,
                             unsigned short* __restrict__ seqs) {
    int bt = blockIdx.x;
    int t = bt % T_;
    int lane = threadIdx.x;
    int idx = ls[bt];
    int pos = idx ? (t + 1) : 0;
    float4 a = ((const float4*)(itab + (size_t)idx * D_))[lane];
    float4 p = ((const float4*)(ptab + (size_t)pos * D_))[lane];
    i32x2 r;
    r[0] = (int)pk2(a.x*16.f+p.x, a.y*16.f+p.y);
    r[1] = (int)pk2(a.z*16.f+p.z, a.w*16.f+p.w);
    ((i32x2*)(seqs + (size_t)bt * D_))[lane] = r;
}

// ---------------- layernorm (bf16 in; bf16 or fp32 out), 4 rows/block ----------------
template<bool F32OUT>
__global__ __launch_bounds__(256) void ln_kernel(const unsigned short* __restrict__ X,
                                                 const float* __restrict__ sc,
                                                 const float* __restrict__ bi,
                                                 void* __restrict__ Y) {
    int row = blockIdx.x * 4 + (threadIdx.x >> 6);
    int lane = threadIdx.x & 63;
    i32x2 xv = ((const i32x2*)(X + (size_t)row * D_))[lane];
    float x0 = bflo((unsigned)xv[0]), x1 = bfhi((unsigned)xv[0]);
    float x2 = bflo((unsigned)xv[1]), x3 = bfhi((unsigned)xv[1]);
    float m = wave_sum(x0 + x1 + x2 + x3) * (1.f / D_);
    float d0 = x0 - m, d1 = x1 - m, d2 = x2 - m, d3 = x3 - m;
    float v = wave_sum(d0*d0 + d1*d1 + d2*d2 + d3*d3) * (1.f / D_);
    float inv = rsqrtf(v + 1e-8f);
    float4 s4 = ((const float4*)sc)[lane];
    float4 b4 = ((const float4*)bi)[lane];
    float r0 = d0*inv*s4.x + b4.x, r1 = d1*inv*s4.y + b4.y;
    float r2 = d2*inv*s4.z + b4.z, r3 = d3*inv*s4.w + b4.w;
    if (F32OUT) {
        float4 r = {r0, r1, r2, r3};
        ((float4*)Y)[(size_t)row * (D_/4) + lane] = r;
    } else {
        i32x2 r;
        r[0] = (int)pk2(r0, r1);
        r[1] = (int)pk2(r2, r3);
        ((i32x2*)Y)[(size_t)row * (D_/4) + lane] = r;   // i32x2 = 4 bf16
    }
}

// ---------------- weight transpose: Wt[n][k] = bf16(W[k][n]) ----------------
__global__ __launch_bounds__(256) void wtrans_kernel(const float* __restrict__ W,
                                                     unsigned short* __restrict__ Wt) {
    __shared__ float tile[64][65];
    int c0 = blockIdx.x * 64, r0 = blockIdx.y * 64, l = blockIdx.z;
    const float* src = W + (size_t)l * DD_;
    unsigned short* dst = Wt + (size_t)l * DD_;
    int tid = threadIdx.x;
#pragma unroll
    for (int rep = 0; rep < 16; ++rep) {
        int idx = rep * 256 + tid;
        int r = idx >> 6, c = idx & 63;
        tile[r][c] = src[(size_t)(r0 + r) * D_ + c0 + c];
    }
    __syncthreads();
#pragma unroll
    for (int rep = 0; rep < 16; ++rep) {
        int idx = rep * 256 + tid;
        int r2 = idx >> 6, c2 = idx & 63;
        dst[(size_t)(c0 + r2) * D_ + r0 + c2] = f2bf(tile[c2][r2]);
    }
}

// zero vtbf pad cols [200,224)
__global__ void vtpad_kernel(unsigned short* __restrict__ vt) {
    if (threadIdx.x < VTP_ - T_)
        vt[(size_t)blockIdx.x * VTP_ + T_ + threadIdx.x] = 0;
}

// ---------------- MFMA GEMM (512 threads / 8 waves; used for Wo) ----------------
// OM: 0 = bf16 flat [m][256]; 1 = bf16 padded [b][208][256].
template<int OM, bool RES>
__global__ __launch_bounds__(512) void gemm_mfma(
    const unsigned short* __restrict__ A, const unsigned short* __restrict__ Wt,
    const float* __restrict__ bias, const unsigned short* res,
    unsigned short* Cout) {
    __shared__ unsigned short sh[2 * 128 * GS_];
    unsigned short* As = sh;
    unsigned short* Ws = sh + 128 * GS_;
    int t = threadIdx.x, lane = t & 63, wv = t >> 6;   // wv 0..7
    int wm = wv >> 1, wn = wv & 1;                     // wm 0..3 (32-row slices)
    int l15 = lane & 15, l4 = lane >> 4;
    int m0 = blockIdx.y * 128, n0 = blockIdx.x * 128;

    f32x4 acc[2][4];
#pragma unroll
    for (int m = 0; m < 2; ++m)
#pragma unroll
        for (int n = 0; n < 4; ++n)
            acc[m][n] = f32x4{0.f, 0.f, 0.f, 0.f};

    for (int k0 = 0; k0 < D_; k0 += 64) {
#pragma unroll
        for (int rep = 0; rep < 2; ++rep) {
            int idx = rep * 512 + t;
            int r = idx >> 3, c8 = (idx & 7) * 8;
            *(i32x4*)&As[r * GS_ + c8] = *(const i32x4*)(A  + (size_t)(m0 + r) * D_ + k0 + c8);
            *(i32x4*)&Ws[r * GS_ + c8] = *(const i32x4*)(Wt + (size_t)(n0 + r) * D_ + k0 + c8);
        }
        __syncthreads();
#pragma unroll
        for (int kk = 0; kk < 2; ++kk) {
            bf16x8 af[2], bf[4];
#pragma unroll
            for (int m = 0; m < 2; ++m)
                af[m] = *(const bf16x8*)&As[(wm*32 + m*16 + l15) * GS_ + kk*32 + l4*8];
#pragma unroll
            for (int n = 0; n < 4; ++n)
                bf[n] = *(const bf16x8*)&Ws[(wn*64 + n*16 + l15) * GS_ + kk*32 + l4*8];
#pragma unroll
            for (int m = 0; m < 2; ++m)
#pragma unroll
                for (int n = 0; n < 4; ++n)
                    acc[m][n] = __builtin_amdgcn_mfma_f32_16x16x32_bf16(af[m], bf[n], acc[m][n], 0, 0, 0);
        }
        __syncthreads();
    }

    unsigned short* Ct = sh;
#pragma unroll
    for (int n = 0; n < 4; ++n) {
        int gnl = wn*64 + n*16 + l15;
        int gn = n0 + gnl;
        float bn = bias[gn];
#pragma unroll
        for (int m = 0; m < 2; ++m) {
#pragma unroll
            for (int i = 0; i < 4; ++i) {
                int gml = wm*32 + m*16 + l4*4 + i;
                int gm = m0 + gml;
                float v = acc[m][n][i] + bn;
                if (RES) v += bflo((unsigned)res[(size_t)gm * D_ + gn]);
                Ct[gml * VS_ + gnl] = f2bf(v);
            }
        }
    }
    __syncthreads();
#pragma unroll
    for (int rep = 0; rep < 4; ++rep) {
        int idx = rep * 512 + t;
        int row = idx >> 4, c8 = (idx & 15) * 8;
        int gm = m0 + row;
        i32x4 w = *(const i32x4*)&Ct[row * VS_ + c8];
        if (OM == 0) {
            *(i32x4*)&Cout[(size_t)gm * D_ + n0 + c8] = w;
        } else {
            int b = gm / 200, tt = gm - b * 200;
            *(i32x4*)&Cout[((size_t)b * TP_ + tt) * D_ + n0 + c8] = w;
        }
    }
}

// ---------------- merged QKV GEMM: blockIdx.z=0 -> Q (from Qn); z=1 -> K+V (from X) ----
__global__ __launch_bounds__(512) void qkv_gemm(
    const unsigned short* __restrict__ Qn, const unsigned short* __restrict__ X,
    const unsigned short* __restrict__ WtQ,
    const unsigned short* __restrict__ WtK, const unsigned short* __restrict__ WtV,
    const float* __restrict__ biasQ, const float* __restrict__ biasK,
    const float* __restrict__ biasV,
    unsigned short* __restrict__ qbf, unsigned short* __restrict__ kbf,
    unsigned short* __restrict__ vtbf) {
    __shared__ unsigned short sh[3 * 128 * GS_];
    int t = threadIdx.x, lane = t & 63, wv = t >> 6;
    int wm = wv >> 1, wn = wv & 1;
    int l15 = lane & 15, l4 = lane >> 4;
    int m0 = blockIdx.y * 128, n0 = blockIdx.x * 128;

    if (blockIdx.z == 0) {
        unsigned short* As = sh;
        unsigned short* Ws = sh + 128 * GS_;
        f32x4 acc[2][4];
#pragma unroll
        for (int m = 0; m < 2; ++m)
#pragma unroll
            for (int n = 0; n < 4; ++n)
                acc[m][n] = f32x4{0.f, 0.f, 0.f, 0.f};

        for (int k0 = 0; k0 < D_; k0 += 64) {
#pragma unroll
            for (int rep = 0; rep < 2; ++rep) {
                int idx = rep * 512 + t;
                int r = idx >> 3, c8 = (idx & 7) * 8;
                *(i32x4*)&As[r * GS_ + c8] = *(const i32x4*)(Qn  + (size_t)(m0 + r) * D_ + k0 + c8);
                *(i32x4*)&Ws[r * GS_ + c8] = *(const i32x4*)(WtQ + (size_t)(n0 + r) * D_ + k0 + c8);
            }
            __syncthreads();
#pragma unroll
            for (int kk = 0; kk < 2; ++kk) {
                bf16x8 af[2], bf[4];
#pragma unroll
                for (int m = 0; m < 2; ++m)
                    af[m] = *(const bf16x8*)&As[(wm*32 + m*16 + l15) * GS_ + kk*32 + l4*8];
#pragma unroll
                for (int n = 0; n < 4; ++n)
                    bf[n] = *(const bf16x8*)&Ws[(wn*64 + n*16 + l15) * GS_ + kk*32 + l4*8];
#pragma unroll
                for (int m = 0; m < 2; ++m)
#pragma unroll
                    for (int n = 0; n < 4; ++n)
                        acc[m][n] = __builtin_amdgcn_mfma_f32_16x16x32_bf16(af[m], bf[n], acc[m][n], 0, 0, 0);
            }
            __syncthreads();
        }

        unsigned short* Ct = sh;
#pragma unroll
        for (int n = 0; n < 4; ++n) {
            int gnl = wn*64 + n*16 + l15;
            float bn = biasQ[n0 + gnl];
#pragma unroll
            for (int m = 0; m < 2; ++m)
#pragma unroll
                for (int i = 0; i < 4; ++i) {
                    int gml = wm*32 + m*16 + l4*4 + i;
                    Ct[gml * VS_ + gnl] = f2bf(acc[m][n][i] + bn);
                }
        }
        __syncthreads();
#pragma unroll
        for (int rep = 0; rep < 4; ++rep) {
            int idx = rep * 512 + t;
            int row = idx >> 4, c8 = (idx & 15) * 8;
            int gm = m0 + row, b = gm / 200, tt = gm - b * 200;
            *(i32x4*)&qbf[((size_t)b * TP_ + tt) * D_ + n0 + c8] =
                *(const i32x4*)&Ct[row * VS_ + c8];
        }
    } else {
        unsigned short* As  = sh;
        unsigned short* WsK = sh + 128 * GS_;
        unsigned short* WsV = sh + 2 * 128 * GS_;
        f32x4 accK[2][4], accV[2][4];
#pragma unroll
        for (int m = 0; m < 2; ++m)
#pragma unroll
            for (int n = 0; n < 4; ++n) {
                accK[m][n] = f32x4{0.f, 0.f, 0.f, 0.f};
                accV[m][n] = f32x4{0.f, 0.f, 0.f, 0.f};
            }

        for (int k0 = 0; k0 < D_; k0 += 64) {
#pragma unroll
            for (int rep = 0; rep < 2; ++rep) {
                int idx = rep * 512 + t;
                int r = idx >> 3, c8 = (idx & 7) * 8;
                *(i32x4*)&As[r * GS_ + c8]  = *(const i32x4*)(X   + (size_t)(m0 + r) * D_ + k0 + c8);
                *(i32x4*)&WsK[r * GS_ + c8] = *(const i32x4*)(WtK + (size_t)(n0 + r) * D_ + k0 + c8);
                *(i32x4*)&WsV[r * GS_ + c8] = *(const i32x4*)(WtV + (size_t)(n0 + r) * D_ + k0 + c8);
            }
            __syncthreads();
#pragma unroll
            for (int kk = 0; kk < 2; ++kk) {
                bf16x8 af[2];
#pragma unroll
                for (int m = 0; m < 2; ++m)
                    af[m] = *(const bf16x8*)&As[(wm*32 + m*16 + l15) * GS_ + kk*32 + l4*8];
#pragma unroll
                for (int n = 0; n < 4; ++n) {
                    bf16x8 bk8 = *(const bf16x8*)&WsK[(wn*64 + n*16 + l15) * GS_ + kk*32 + l4*8];
                    bf16x8 bv8 = *(const bf16x8*)&WsV[(wn*64 + n*16 + l15) * GS_ + kk*32 + l4*8];
#pragma unroll
                    for (int m = 0; m < 2; ++m) {
                        accK[m][n] = __builtin_amdgcn_mfma_f32_16x16x32_bf16(af[m], bk8, accK[m][n], 0, 0, 0);
                        accV[m][n] = __builtin_amdgcn_mfma_f32_16x16x32_bf16(af[m], bv8, accV[m][n], 0, 0, 0);
                    }
                }
            }
            __syncthreads();
        }

        unsigned short* Ct = sh;
#pragma unroll
        for (int n = 0; n < 4; ++n) {
            int gnl = wn*64 + n*16 + l15;
            float bnK = biasK[n0 + gnl];
#pragma unroll
            for (int m = 0; m < 2; ++m)
#pragma unroll
                for (int i = 0; i < 4; ++i) {
                    int gml = wm*32 + m*16 + l4*4 + i;
                    Ct[gml * VS_ + gnl] = f2bf(accK[m][n][i] + bnK);
                }
        }
        __syncthreads();
#pragma unroll
        for (int rep = 0; rep < 4; ++rep) {
            int idx = rep * 512 + t;
            int row = idx >> 4, c8 = (idx & 15) * 8;
            int gm = m0 + row, b = gm / 200, tt = gm - b * 200;
            *(i32x4*)&kbf[((size_t)b * TP_ + tt) * D_ + n0 + c8] =
                *(const i32x4*)&Ct[row * VS_ + c8];
        }
        __syncthreads();

        unsigned short* Vt = sh;
#pragma unroll
        for (int n = 0; n < 4; ++n) {
            int gnl = wn*64 + n*16 + l15;
            float bnV = biasV[n0 + gnl];
#pragma unroll
            for (int m = 0; m < 2; ++m)
#pragma unroll
                for (int i = 0; i < 4; ++i) {
                    int gml = wm*32 + m*16 + l4*4 + i;
                    Vt[gnl * VS_ + gml] = f2bf(accV[m][n][i] + bnV);
                }
        }
        __syncthreads();
#pragma unroll
        for (int rep = 0; rep < 4; ++rep) {
            int idx = rep * 512 + t;
            int row = idx >> 4, c8 = (idx & 15) * 8;
            int gn = n0 + row, hh = gn >> 6, dk = gn & 63;
            int gm = m0 + c8, b = gm / 200, tt = gm - b * 200;
            *(i32x4*)&vtbf[(((size_t)b * H_ + hh) * 64 + dk) * VTP_ + tt] =
                *(const i32x4*)&Vt[row * VS_ + c8];
        }
    }
}

// ---------------- fused FFN: LN2 + relu(y@W1+b1)@W2 + b2 + y (32-row blocks) ---
__global__ __launch_bounds__(256) void ffn_fused(
    const unsigned short* __restrict__ S,
    const float* __restrict__ ln_s, const float* __restrict__ ln_b,
    const unsigned short* __restrict__ Wt1, const float* __restrict__ b1,
    const unsigned short* __restrict__ Wt2, const float* __restrict__ b2,
    unsigned short* __restrict__ OUT) {
    __shared__ unsigned short Alds[32 * FS_];
    __shared__ unsigned short Tlds[32 * FS_];
    __shared__ unsigned short Ws[256 * GS_];
    int t = threadIdx.x, lane = t & 63, wv = t >> 6;
    int l15 = lane & 15, l4 = lane >> 4;
    int m0 = blockIdx.x * 32;

    {
        int r = t >> 3, c = (t & 7) * 32;
        const unsigned short* src = S + (size_t)(m0 + r) * D_ + c;
        i32x4 buf[4];
#pragma unroll
        for (int j = 0; j < 4; ++j) buf[j] = ((const i32x4*)src)[j];
        float sum = 0.f;
#pragma unroll
        for (int j = 0; j < 4; ++j)
#pragma unroll
            for (int q = 0; q < 4; ++q)
                sum += bflo((unsigned)buf[j][q]) + bfhi((unsigned)buf[j][q]);
        sum += __shfl_xor(sum, 1);
        sum += __shfl_xor(sum, 2);
        sum += __shfl_xor(sum, 4);
        float mean = sum * (1.f / D_);
        float var = 0.f;
#pragma unroll
        for (int j = 0; j < 4; ++j)
#pragma unroll
            for (int q = 0; q < 4; ++q) {
                float a0 = bflo((unsigned)buf[j][q]) - mean;
                float a1 = bfhi((unsigned)buf[j][q]) - mean;
                var += a0*a0 + a1*a1;
            }
        var += __shfl_xor(var, 1);
        var += __shfl_xor(var, 2);
        var += __shfl_xor(var, 4);
        float inv = rsqrtf(var * (1.f / D_) + 1e-8f);
#pragma unroll
        for (int j = 0; j < 4; ++j) {
            int cc = c + j * 8;
            float4 sa = *(const float4*)&ln_s[cc];
            float4 sb = *(const float4*)&ln_s[cc + 4];
            float4 ba = *(const float4*)&ln_b[cc];
            float4 bb = *(const float4*)&ln_b[cc + 4];
            float y0 = (bflo((unsigned)buf[j][0]) - mean) * inv * sa.x + ba.x;
            float y1 = (bfhi((unsigned)buf[j][0]) - mean) * inv * sa.y + ba.y;
            float y2 = (bflo((unsigned)buf[j][1]) - mean) * inv * sa.z + ba.z;
            float y3 = (bfhi((unsigned)buf[j][1]) - mean) * inv * sa.w + ba.w;
            float y4 = (bflo((unsigned)buf[j][2]) - mean) * inv * sb.x + bb.x;
            float y5 = (bfhi((unsigned)buf[j][2]) - mean) * inv * sb.y + bb.y;
            float y6 = (bflo((unsigned)buf[j][3]) - mean) * inv * sb.z + bb.z;
            float y7 = (bfhi((unsigned)buf[j][3]) - mean) * inv * sb.w + bb.w;
            i32x4 w;
            w[0] = (int)pk2(y0, y1);
            w[1] = (int)pk2(y2, y3);
            w[2] = (int)pk2(y4, y5);
            w[3] = (int)pk2(y6, y7);
            *(i32x4*)&Alds[r * FS_ + cc] = w;
        }
    }
    __syncthreads();

    f32x4 acc[2][4];
#pragma unroll
    for (int m = 0; m < 2; ++m)
#pragma unroll
        for (int n = 0; n < 4; ++n)
            acc[m][n] = f32x4{0.f, 0.f, 0.f, 0.f};
    for (int k0 = 0; k0 < D_; k0 += 64) {
#pragma unroll
        for (int rep = 0; rep < 8; ++rep) {
            int idx = rep * 256 + t;
            int rr = idx >> 3, c8 = (idx & 7) * 8;
            *(i32x4*)&Ws[rr * GS_ + c8] = *(const i32x4*)(Wt1 + (size_t)rr * D_ + k0 + c8);
        }
        __syncthreads();
#pragma unroll
        for (int kk = 0; kk < 2; ++kk) {
            bf16x8 af[2], bf[4];
#pragma unroll
            for (int m = 0; m < 2; ++m)
                af[m] = *(const bf16x8*)&Alds[(m*16 + l15) * FS_ + k0 + kk*32 + l4*8];
#pragma unroll
            for (int n = 0; n < 4; ++n)
                bf[n] = *(const bf16x8*)&Ws[(wv*64 + n*16 + l15) * GS_ + kk*32 + l4*8];
#pragma unroll
            for (int m = 0; m < 2; ++m)
#pragma unroll
                for (int n = 0; n < 4; ++n)
                    acc[m][n] = __builtin_amdgcn_mfma_f32_16x16x32_bf16(af[m], bf[n], acc[m][n], 0, 0, 0);
        }
        __syncthreads();
    }
#pragma unroll
    for (int n = 0; n < 4; ++n) {
        int gn = wv*64 + n*16 + l15;
        float bn = b1[gn];
#pragma unroll
        for (int m = 0; m < 2; ++m)
#pragma unroll
            for (int i = 0; i < 4; ++i)
                Tlds[(m*16 + l4*4 + i) * FS_ + gn] = f2bf(fmaxf(acc[m][n][i] + bn, 0.f));
    }
    __syncthreads();

#pragma unroll
    for (int m = 0; m < 2; ++m)
#pragma unroll
        for (int n = 0; n < 4; ++n)
            acc[m][n] = f32x4{0.f, 0.f, 0.f, 0.f};
    for (int k0 = 0; k0 < D_; k0 += 64) {
#pragma unroll
        for (int rep = 0; rep < 8; ++rep) {
            int idx = rep * 256 + t;
            int rr = idx >> 3, c8 = (idx & 7) * 8;
            *(i32x4*)&Ws[rr * GS_ + c8] = *(const i32x4*)(Wt2 + (size_t)rr * D_ + k0 + c8);
        }
        __syncthreads();
#pragma unroll
        for (int kk = 0; kk < 2; ++kk) {
            bf16x8 af[2], bf[4];
#pragma unroll
            for (int m = 0; m < 2; ++m)
                af[m] = *(const bf16x8*)&Tlds[(m*16 + l15) * FS_ + k0 + kk*32 + l4*8];
#pragma unroll
            for (int n = 0; n < 4; ++n)
                bf[n] = *(const bf16x8*)&Ws[(wv*64 + n*16 + l15) * GS_ + kk*32 + l4*8];
#pragma unroll
            for (int m = 0; m < 2; ++m)
#pragma unroll
                for (int n = 0; n < 4; ++n)
                    acc[m][n] = __builtin_amdgcn_mfma_f32_16x16x32_bf16(af[m], bf[n], acc[m][n], 0, 0, 0);
        }
        __syncthreads();
    }
#pragma unroll
    for (int n = 0; n < 4; ++n) {
        int gn = wv*64 + n*16 + l15;
        float bn = b2[gn];
#pragma unroll
        for (int m = 0; m < 2; ++m) {
#pragma unroll
            for (int i = 0; i < 4; ++i) {
                int row = m*16 + l4*4 + i;
                float v = acc[m][n][i] + bn + bflo((unsigned)Alds[row * FS_ + gn]);
                Tlds[row * FS_ + gn] = f2bf(v);
            }
        }
    }
    __syncthreads();
#pragma unroll
    for (int rep = 0; rep < 4; ++rep) {
        int idx = rep * 256 + t;
        int row = idx >> 5, c8 = (idx & 31) * 8;
        *(i32x4*)&OUT[(size_t)(m0 + row) * D_ + c8] = *(const i32x4*)&Tlds[row * FS_ + c8];
    }
}

// ---------------- MFMA attention: r19 body; 4 waves = 4 heads of one (b,qt) ----
// Block o = b*13 + qt (b outermost -> K/V L2 locality preserved, unlike r23);
// equal-qt waves -> equal duration; per-wave Olds -> no barrier.
// Grid 3328 = 8 x 416 XCD-swizzled.
template<bool DEC>
__global__ __launch_bounds__(256) void attn_mfma(
    const unsigned short* __restrict__ qbf,   // [b][208][256]
    const unsigned short* __restrict__ kbf,   // [b][208][256]
    const unsigned short* __restrict__ vtbf,  // [b*4+h][64][224]
    const float* __restrict__ cm,
    unsigned short* __restrict__ obf) {       // [bt][256]
    __shared__ unsigned short OldsAll[4 * 16 * 72];
    int wvid = threadIdx.x >> 6;
    unsigned short* Olds = &OldsAll[wvid * 16 * 72];
    int o = ((blockIdx.x & 7) * 416) + (blockIdx.x >> 3);
    int b = o / 13;
    int qt = o - b * 13;
    int h = wvid;
    int lane = threadIdx.x & 63;
    int l15 = lane & 15, l4 = lane >> 4;
    int q0 = qt * 16;
    int qr = q0 + l15;
    const f32x4 zero = {0.f, 0.f, 0.f, 0.f};

    size_t qkb = ((size_t)b * TP_) * D_ + h * 64;
    const unsigned short* qp = qbf + qkb + (size_t)(q0 + l15) * D_ + l4 * 8;
    bf16x8 bq0 = *(const bf16x8*)qp;
    bf16x8 bq1 = *(const bf16x8*)(qp + 32);

    // this lane's cm row (kk contiguous -> float4); shared by all 4 heads
    const float* cmrow = DEC ? (cm + ((size_t)b * T_ + qr) * T_) : cm;

    size_t vbase = ((size_t)(b * H_ + h)) * 64 * VTP_;
    int sA = l15 + ((l4 & 1) << 5);
    int sB = sA + 16;
    bool lo4 = (l4 < 2);

    float m = -3e38f, l = 0.f;
    f32x4 O[4] = {zero, zero, zero, zero};

    int npair = (qt >> 1) + 1;
    for (int p = 0; p < npair; ++p) {
        int kt0 = 2 * p;
        bool hasOdd = (kt0 + 1 <= qt);

        f32x4 sv0, sv1;
        {
            const unsigned short* kp = kbf + qkb + (size_t)(kt0 * 16 + l15) * D_ + l4 * 8;
            bf16x8 ak0 = *(const bf16x8*)kp;
            bf16x8 ak1 = *(const bf16x8*)(kp + 32);
            __builtin_amdgcn_s_setprio(1);
            f32x4 acc = __builtin_amdgcn_mfma_f32_16x16x32_bf16(ak0, bq0, zero, 0, 0, 0);
            acc = __builtin_amdgcn_mfma_f32_16x16x32_bf16(ak1, bq1, acc, 0, 0, 0);
            __builtin_amdgcn_s_setprio(0);
            float cmarr[4] = {0.f, 0.f, 0.f, 0.f};
            if (DEC) {
                float4 cq = *(const float4*)&cmrow[kt0 * 16 + l4 * 4];
                cmarr[0] = cq.x; cmarr[1] = cq.y; cmarr[2] = cq.z; cmarr[3] = cq.w;
            }
#pragma unroll
            for (int i = 0; i < 4; ++i) {
                int kk = kt0 * 16 + l4 * 4 + i;
                float s = acc[i] * 0.125f;
                bool vld = (qr < T_) && (kk < T_);
                if (!vld) s = -1e9f;
                else {
                    if (kk > qr) s = -1e9f;   // mask BEFORE cm multiply (as reference)
                    if (DEC) s *= (1.0f + 0.5f * cmarr[i]);
                }
                sv0[i] = s;
            }
        }
        if (hasOdd) {
            const unsigned short* kp = kbf + qkb + (size_t)((kt0 + 1) * 16 + l15) * D_ + l4 * 8;
            bf16x8 ak0 = *(const bf16x8*)kp;
            bf16x8 ak1 = *(const bf16x8*)(kp + 32);
            __builtin_amdgcn_s_setprio(1);
            f32x4 acc = __builtin_amdgcn_mfma_f32_16x16x32_bf16(ak0, bq0, zero, 0, 0, 0);
            acc = __builtin_amdgcn_mfma_f32_16x16x32_bf16(ak1, bq1, acc, 0, 0, 0);
            __builtin_amdgcn_s_setprio(0);
            float cmarr[4] = {0.f, 0.f, 0.f, 0.f};
            if (DEC) {
                float4 cq = *(const float4*)&cmrow[(kt0 + 1) * 16 + l4 * 4];
                cmarr[0] = cq.x; cmarr[1] = cq.y; cmarr[2] = cq.z; cmarr[3] = cq.w;
            }
#pragma unroll
            for (int i = 0; i < 4; ++i) {
                int kk = (kt0 + 1) * 16 + l4 * 4 + i;
                float s = acc[i] * 0.125f;
                bool vld = (qr < T_) && (kk < T_);
                if (!vld) s = -1e9f;
                else {
                    if (kk > qr) s = -1e9f;
                    if (DEC) s *= (1.0f + 0.5f * cmarr[i]);
                }
                sv1[i] = s;
            }
        }

        float tm = fmaxf(fmaxf(sv0[0], sv0[1]), fmaxf(sv0[2], sv0[3]));
        if (hasOdd) {
            float tm1 = fmaxf(fmaxf(sv1[0], sv1[1]), fmaxf(sv1[2], sv1[3]));
            tm = fmaxf(tm, tm1);
        }
        tm = fmaxf(tm, __shfl_xor(tm, 16));
        tm = fmaxf(tm, __shfl_xor(tm, 32));
        float m_new = fmaxf(m, tm);
        float sc = __expf(m - m_new);
        m = m_new;
        l *= sc;
#pragma unroll
        for (int i = 0; i < 4; ++i) {
            float osc = __shfl(sc, l4 * 4 + i);
#pragma unroll
            for (int dt = 0; dt < 4; ++dt) O[dt][i] *= osc;
        }

        float p0[4], p1[4];
#pragma unroll
        for (int i = 0; i < 4; ++i) {
            p0[i] = __expf(sv0[i] - m);
            l += p0[i];
        }
        if (hasOdd) {
#pragma unroll
            for (int i = 0; i < 4; ++i) {
                p1[i] = __expf(sv1[i] - m);
                l += p1[i];
            }
        } else {
#pragma unroll
            for (int i = 0; i < 4; ++i) p1[i] = 0.f;
        }

        unsigned pk0a = pk2(p0[0], p0[1]), pk0b = pk2(p0[2], p0[3]);
        unsigned pk1a = pk2(p1[0], p1[1]), pk1b = pk2(p1[2], p1[3]);
        unsigned e0 = (unsigned)__shfl((int)pk0a, sA);
        unsigned e1 = (unsigned)__shfl((int)pk0b, sA);
        unsigned e2 = (unsigned)__shfl((int)pk0a, sB);
        unsigned e3 = (unsigned)__shfl((int)pk0b, sB);
        unsigned o0 = (unsigned)__shfl((int)pk1a, sA);
        unsigned o1 = (unsigned)__shfl((int)pk1b, sA);
        unsigned o2 = (unsigned)__shfl((int)pk1a, sB);
        unsigned o3 = (unsigned)__shfl((int)pk1b, sB);
        frag8 pa;
        pa.u[0] = lo4 ? e0 : o0;
        pa.u[1] = lo4 ? e1 : o1;
        pa.u[2] = lo4 ? e2 : o2;
        pa.u[3] = lo4 ? e3 : o3;

        __builtin_amdgcn_s_setprio(1);
#pragma unroll
        for (int dt = 0; dt < 4; ++dt) {
            bf16x8 vf = *(const bf16x8*)&vtbf[vbase + (size_t)(dt * 16 + l15) * VTP_ + p * 32 + l4 * 8];
            O[dt] = __builtin_amdgcn_mfma_f32_16x16x32_bf16(pa.v, vf, O[dt], 0, 0, 0);
        }
        __builtin_amdgcn_s_setprio(0);
    }

    float L = l;
    L += __shfl_xor(L, 16);
    L += __shfl_xor(L, 32);
    float inv = 1.f / L;
    // per-wave Olds slice: intra-wave LDS ordering only (no __syncthreads needed)
#pragma unroll
    for (int i = 0; i < 4; ++i) {
        float oin = __shfl(inv, l4 * 4 + i);
#pragma unroll
        for (int dt = 0; dt < 4; ++dt)
            Olds[(l4 * 4 + i) * 72 + dt * 16 + l15] = f2bf(O[dt][i] * oin);
    }
#pragma unroll
    for (int rep = 0; rep < 2; ++rep) {
        int idx = rep * 64 + lane;
        int row = idx >> 3, c8 = (idx & 7) * 8;
        int qrow = q0 + row;
        if (qrow < T_)
            *(i32x4*)&obf[((size_t)(b * T_) + qrow) * D_ + h * 64 + c8] =
                *(const i32x4*)&Olds[row * 72 + c8];
    }
}

// ---------------- cov (bf16 Z in; row mean computed inline per wave) ----------------
__global__ __launch_bounds__(512) void cov_mfma(const unsigned short* __restrict__ Z,
                                                float* __restrict__ cm) {
    __shared__ unsigned short Zb[208 * ZS_];
    int b = blockIdx.x;
    int tid = threadIdx.x, lane = tid & 63, wv = tid >> 6;
    int l15 = lane & 15, l4 = lane >> 4;

    for (int i = tid; i < T_ * 64; i += 512) {
        int t = i >> 6, c4 = (i & 63) << 2;
        i32x2 z = *(const i32x2*)(Z + ((size_t)b * T_ + t) * D_ + c4);
        float z0 = bflo((unsigned)z[0]), z1 = bfhi((unsigned)z[0]);
        float z2 = bflo((unsigned)z[1]), z3 = bfhi((unsigned)z[1]);
        float mean = wave_sum(z0 + z1 + z2 + z3) * (1.f / D_);
        unsigned* p = (unsigned*)&Zb[t * ZS_ + c4];
        p[0] = pk2(z0 - mean, z1 - mean);
        p[1] = pk2(z2 - mean, z3 - mean);
    }
    for (int i = tid; i < 8 * ZS_; i += 512) Zb[T_ * ZS_ + i] = 0;
    __syncthreads();

    for (int job = wv; job < 91; job += 8) {
        int ti = 0;
        while ((ti + 1) * (ti + 2) / 2 <= job) ++ti;
        int tj = job - ti * (ti + 1) / 2;
        f32x4 acc = {0.f, 0.f, 0.f, 0.f};
#pragma unroll
        for (int s = 0; s < 8; ++s) {
            bf16x8 a  = *(const bf16x8*)&Zb[(ti * 16 + l15) * ZS_ + s * 32 + l4 * 8];
            bf16x8 bb = *(const bf16x8*)&Zb[(tj * 16 + l15) * ZS_ + s * 32 + l4 * 8];
            acc = __builtin_amdgcn_mfma_f32_16x16x32_bf16(a, bb, acc, 0, 0, 0);
        }
#pragma unroll
        for (int i = 0; i < 4; ++i) {
            int t = ti * 16 + l4 * 4 + i, s2 = tj * 16 + l15;
            float vv = fminf(acc[i] * (1.f / 255.f), 3.0f);
            if (t < T_ && s2 < T_) {
                cm[((size_t)b * T_ + t) * T_ + s2] = vv;
                cm[((size_t)b * T_ + s2) * T_ + t] = vv;
            }
        }
    }
}

extern "C" void kernel_launch(void* const* d_in, const int* in_sizes, int n_in,
                              void* d_out, int out_size, void* d_ws, size_t ws_size,
                              hipStream_t stream) {
    const int*   log_seqs = (const int*)  d_in[0];
    const float* item_tab = (const float*)d_in[1];
    const float* pos_tab  = (const float*)d_in[2];
    const float* ln1_s = (const float*)d_in[3];
    const float* ln1_b = (const float*)d_in[4];
    const float* Wq = (const float*)d_in[5];
    const float* bq = (const float*)d_in[6];
    const float* Wk = (const float*)d_in[7];
    const float* bk = (const float*)d_in[8];
    const float* Wv = (const float*)d_in[9];
    const float* bv = (const float*)d_in[10];
    const float* Wo = (const float*)d_in[11];
    const float* bo = (const float*)d_in[12];
    const float* ln2_s = (const float*)d_in[13];
    const float* ln2_b = (const float*)d_in[14];
    const float* W1 = (const float*)d_in[15];
    const float* b1 = (const float*)d_in[16];
    const float* W2 = (const float*)d_in[17];
    const float* b2 = (const float*)d_in[18];
    const float* last_s = (const float*)d_in[19];
    const float* last_b = (const float*)d_in[20];

    const size_t NTD = (size_t)BT_ * D_;
    float* cmask = (float*)d_ws;                               // B*T*T fp32
    unsigned short* act = (unsigned short*)(cmask + (size_t)B_ * T_ * T_);
    unsigned short* s0   = act;              // seqs / layer-3 out
    unsigned short* s1   = s0 + NTD;         // causal_z / layer-2 out
    unsigned short* Qn   = s1 + NTD;         // ln1 out, then s (in-place)
    unsigned short* vb   = Qn + NTD;         // obf
    unsigned short* qbf  = vb + NTD;                         // [B][208][256]
    unsigned short* kbf  = qbf + (size_t)B_ * TP_ * D_;      // [B][208][256]
    unsigned short* vtbf = kbf + (size_t)B_ * TP_ * D_;      // [B*H][64][224]
    unsigned short* wtb  = vtbf + (size_t)B_ * H_ * 64 * VTP_;

    unsigned short* wtq = wtb;
    unsigned short* wtk = wtb + 4 * (size_t)DD_;
    unsigned short* wtv = wtb + 8 * (size_t)DD_;
    unsigned short* wto = wtb + 12 * (size_t)DD_;
    unsigned short* wt1 = wtb + 16 * (size_t)DD_;
    unsigned short* wt2 = wtb + 20 * (size_t)DD_;

    // transpose only layers 1..3 (layer 0 unused: causal loop keeps only layer 1)
    dim3 tg(4, 4, 3);
    wtrans_kernel<<<tg, 256, 0, stream>>>(Wq + DD_, wtq + DD_);
    wtrans_kernel<<<tg, 256, 0, stream>>>(Wk + DD_, wtk + DD_);
    wtrans_kernel<<<tg, 256, 0, stream>>>(Wv + DD_, wtv + DD_);
    wtrans_kernel<<<tg, 256, 0, stream>>>(Wo + DD_, wto + DD_);
    wtrans_kernel<<<tg, 256, 0, stream>>>(W1 + DD_, wt1 + DD_);
    wtrans_kernel<<<tg, 256, 0, stream>>>(W2 + DD_, wt2 + DD_);
    vtpad_kernel<<<B_ * H_ * 64, 32, 0, stream>>>(vtbf);

    dim3 gg(2, 400);        // N/128, M/128 (Wo gemm)
    dim3 gq(2, 400, 2);     // merged QKV: z=0 Q, z=1 KV

    auto encoder = [&](const unsigned short* X, unsigned short* OUT, int i, const float* cmp) {
        ln_kernel<false><<<BT_/4, 256, 0, stream>>>(X, ln1_s + i*D_, ln1_b + i*D_, Qn);
        qkv_gemm<<<gq, 512, 0, stream>>>(Qn, X,
                                         wtq + (size_t)i*DD_, wtk + (size_t)i*DD_, wtv + (size_t)i*DD_,
                                         bq + i*D_, bk + i*D_, bv + i*D_,
                                         qbf, kbf, vtbf);
        if (cmp) attn_mfma<true ><<<3328, 256, 0, stream>>>(qbf, kbf, vtbf, cmp, vb);
        else     attn_mfma<false><<<3328, 256, 0, stream>>>(qbf, kbf, vtbf, nullptr, vb);
        // s = Qn + vb @ Wo + bo  (in-place into Qn; element-exclusive)
        gemm_mfma<0,true><<<gg, 512, 0, stream>>>(vb, wto + (size_t)i*DD_, bo + i*D_, Qn, Qn);
        // OUT = relu(LN2(s)@W1+b1)@W2 + b2 + LN2(s)
        ffn_fused<<<BT_/32, 256, 0, stream>>>(Qn, ln2_s + i*D_, ln2_b + i*D_,
                                              wt1 + (size_t)i*DD_, b1 + i*D_,
                                              wt2 + (size_t)i*DD_, b2 + i*D_, OUT);
    };

    embed_kernel<<<BT_, 64, 0, stream>>>(log_seqs, item_tab, pos_tab, s0);

    // causal loop applies each layer to ORIGINAL seqs -> only layer 1 survives
    encoder(s0, s1, 1, nullptr);

    cov_mfma<<<B_, 512, 0, stream>>>(s1, cmask);

    encoder(s0, s1, 2, cmask);
    encoder(s1, s0, 3, cmask);

    ln_kernel<true><<<BT_/4, 256, 0, stream>>>(s0, last_s, last_b, (float*)d_out);
}

// Round 28
// 654.287 us; speedup vs baseline: 1.0185x; 1.0185x over previous
//
#include <hip/hip_runtime.h>
#include <hip/hip_bf16.h>

#define B_ 256
#define T_ 200
#define D_ 256
#define H_ 4
#define BT_ (B_*T_)
#define DD_ (D_*D_)
#define GS_ 72     // gemm LDS stride (64 + 8 pad)
#define TP_ 208    // padded token rows per batch for qbf/kbf
#define VTP_ 224   // vtbf row length (7*32)
#define ZS_ 264    // cov Zb stride
#define FS_ 264    // ffn Alds/Tlds stride (256 + 8)
#define VS_ 136    // epilogue LDS transpose stride (128 + 8)

typedef __attribute__((ext_vector_type(4))) float  f32x4;
typedef __attribute__((ext_vector_type(8))) __bf16 bf16x8;
typedef __attribute__((ext_vector_type(4))) int    i32x4;
typedef __attribute__((ext_vector_type(2))) int    i32x2;

union frag8 { unsigned u[4]; bf16x8 v; };

__device__ __forceinline__ unsigned short f2bf(float f) {
    unsigned u = __float_as_uint(f);
    u += 0x7FFFu + ((u >> 16) & 1u);          // RNE to bf16
    return (unsigned short)(u >> 16);
}
__device__ __forceinline__ unsigned pk2(float lo, float hi) {
    return (unsigned)f2bf(lo) | ((unsigned)f2bf(hi) << 16);
}
__device__ __forceinline__ float bflo(unsigned u) { return __uint_as_float(u << 16); }
__device__ __forceinline__ float bfhi(unsigned u) { return __uint_as_float(u & 0xFFFF0000u); }

__device__ __forceinline__ float wave_sum(float v) {
#pragma unroll
    for (int o = 32; o >= 1; o >>= 1) v += __shfl_xor(v, o);
    return v;
}

// ---------------- embed (bf16 out) ----------------
__global__ void embed_kernel(const int* __restrict__ ls,
                             const float* __restrict__ itab,
                             const float* __restrict__ ptab,
                             unsigned short* __restrict__ seqs) {
    int bt = blockIdx.x;
    int t = bt % T_;
    int lane = threadIdx.x;
    int idx = ls[bt];
    int pos = idx ? (t + 1) : 0;
    float4 a = ((const float4*)(itab + (size_t)idx * D_))[lane];
    float4 p = ((const float4*)(ptab + (size_t)pos * D_))[lane];
    i32x2 r;
    r[0] = (int)pk2(a.x*16.f+p.x, a.y*16.f+p.y);
    r[1] = (int)pk2(a.z*16.f+p.z, a.w*16.f+p.w);
    ((i32x2*)(seqs + (size_t)bt * D_))[lane] = r;
}

// ---------------- layernorm (bf16 in; bf16 or fp32 out), 4 rows/block ----------------
template<bool F32OUT>
__global__ __launch_bounds__(256) void ln_kernel(const unsigned short* __restrict__ X,
                                                 const float* __restrict__ sc,
                                                 const float* __restrict__ bi,
                                                 void* __restrict__ Y) {
    int row = blockIdx.x * 4 + (threadIdx.x >> 6);
    int lane = threadIdx.x & 63;
    i32x2 xv = ((const i32x2*)(X + (size_t)row * D_))[lane];
    float x0 = bflo((unsigned)xv[0]), x1 = bfhi((unsigned)xv[0]);
    float x2 = bflo((unsigned)xv[1]), x3 = bfhi((unsigned)xv[1]);
    float m = wave_sum(x0 + x1 + x2 + x3) * (1.f / D_);
    float d0 = x0 - m, d1 = x1 - m, d2 = x2 - m, d3 = x3 - m;
    float v = wave_sum(d0*d0 + d1*d1 + d2*d2 + d3*d3) * (1.f / D_);
    float inv = rsqrtf(v + 1e-8f);
    float4 s4 = ((const float4*)sc)[lane];
    float4 b4 = ((const float4*)bi)[lane];
    float r0 = d0*inv*s4.x + b4.x, r1 = d1*inv*s4.y + b4.y;
    float r2 = d2*inv*s4.z + b4.z, r3 = d3*inv*s4.w + b4.w;
    if (F32OUT) {
        float4 r = {r0, r1, r2, r3};
        ((float4*)Y)[(size_t)row * (D_/4) + lane] = r;
    } else {
        i32x2 r;
        r[0] = (int)pk2(r0, r1);
        r[1] = (int)pk2(r2, r3);
        ((i32x2*)Y)[(size_t)row * (D_/4) + lane] = r;   // i32x2 = 4 bf16
    }
}

// ---------------- weight transpose: Wt[n][k] = bf16(W[k][n]) ----------------
__global__ __launch_bounds__(256) void wtrans_kernel(const float* __restrict__ W,
                                                     unsigned short* __restrict__ Wt) {
    __shared__ float tile[64][65];
    int c0 = blockIdx.x * 64, r0 = blockIdx.y * 64, l = blockIdx.z;
    const float* src = W + (size_t)l * DD_;
    unsigned short* dst = Wt + (size_t)l * DD_;
    int tid = threadIdx.x;
#pragma unroll
    for (int rep = 0; rep < 16; ++rep) {
        int idx = rep * 256 + tid;
        int r = idx >> 6, c = idx & 63;
        tile[r][c] = src[(size_t)(r0 + r) * D_ + c0 + c];
    }
    __syncthreads();
#pragma unroll
    for (int rep = 0; rep < 16; ++rep) {
        int idx = rep * 256 + tid;
        int r2 = idx >> 6, c2 = idx & 63;
        dst[(size_t)(c0 + r2) * D_ + r0 + c2] = f2bf(tile[c2][r2]);
    }
}

// zero vtbf pad cols [200,224)
__global__ void vtpad_kernel(unsigned short* __restrict__ vt) {
    if (threadIdx.x < VTP_ - T_)
        vt[(size_t)blockIdx.x * VTP_ + T_ + threadIdx.x] = 0;
}

// ---------------- MFMA GEMM (512 threads / 8 waves; used for Wo) ----------------
// OM: 0 = bf16 flat [m][256]; 1 = bf16 padded [b][208][256].
template<int OM, bool RES>
__global__ __launch_bounds__(512) void gemm_mfma(
    const unsigned short* __restrict__ A, const unsigned short* __restrict__ Wt,
    const float* __restrict__ bias, const unsigned short* res,
    unsigned short* Cout) {
    __shared__ unsigned short sh[2 * 128 * GS_];
    unsigned short* As = sh;
    unsigned short* Ws = sh + 128 * GS_;
    int t = threadIdx.x, lane = t & 63, wv = t >> 6;   // wv 0..7
    int wm = wv >> 1, wn = wv & 1;                     // wm 0..3 (32-row slices)
    int l15 = lane & 15, l4 = lane >> 4;
    int m0 = blockIdx.y * 128, n0 = blockIdx.x * 128;

    f32x4 acc[2][4];
#pragma unroll
    for (int m = 0; m < 2; ++m)
#pragma unroll
        for (int n = 0; n < 4; ++n)
            acc[m][n] = f32x4{0.f, 0.f, 0.f, 0.f};

    for (int k0 = 0; k0 < D_; k0 += 64) {
#pragma unroll
        for (int rep = 0; rep < 2; ++rep) {
            int idx = rep * 512 + t;
            int r = idx >> 3, c8 = (idx & 7) * 8;
            *(i32x4*)&As[r * GS_ + c8] = *(const i32x4*)(A  + (size_t)(m0 + r) * D_ + k0 + c8);
            *(i32x4*)&Ws[r * GS_ + c8] = *(const i32x4*)(Wt + (size_t)(n0 + r) * D_ + k0 + c8);
        }
        __syncthreads();
#pragma unroll
        for (int kk = 0; kk < 2; ++kk) {
            bf16x8 af[2], bf[4];
#pragma unroll
            for (int m = 0; m < 2; ++m)
                af[m] = *(const bf16x8*)&As[(wm*32 + m*16 + l15) * GS_ + kk*32 + l4*8];
#pragma unroll
            for (int n = 0; n < 4; ++n)
                bf[n] = *(const bf16x8*)&Ws[(wn*64 + n*16 + l15) * GS_ + kk*32 + l4*8];
#pragma unroll
            for (int m = 0; m < 2; ++m)
#pragma unroll
                for (int n = 0; n < 4; ++n)
                    acc[m][n] = __builtin_amdgcn_mfma_f32_16x16x32_bf16(af[m], bf[n], acc[m][n], 0, 0, 0);
        }
        __syncthreads();
    }

    unsigned short* Ct = sh;
#pragma unroll
    for (int n = 0; n < 4; ++n) {
        int gnl = wn*64 + n*16 + l15;
        int gn = n0 + gnl;
        float bn = bias[gn];
#pragma unroll
        for (int m = 0; m < 2; ++m) {
#pragma unroll
            for (int i = 0; i < 4; ++i) {
                int gml = wm*32 + m*16 + l4*4 + i;
                int gm = m0 + gml;
                float v = acc[m][n][i] + bn;
                if (RES) v += bflo((unsigned)res[(size_t)gm * D_ + gn]);
                Ct[gml * VS_ + gnl] = f2bf(v);
            }
        }
    }
    __syncthreads();
#pragma unroll
    for (int rep = 0; rep < 4; ++rep) {
        int idx = rep * 512 + t;
        int row = idx >> 4, c8 = (idx & 15) * 8;
        int gm = m0 + row;
        i32x4 w = *(const i32x4*)&Ct[row * VS_ + c8];
        if (OM == 0) {
            *(i32x4*)&Cout[(size_t)gm * D_ + n0 + c8] = w;
        } else {
            int b = gm / 200, tt = gm - b * 200;
            *(i32x4*)&Cout[((size_t)b * TP_ + tt) * D_ + n0 + c8] = w;
        }
    }
}

// ---------------- merged QKV GEMM: blockIdx.z=0 -> Q (from Qn); z=1 -> K+V (from X) ----
// One launch so Q and KV waves co-schedule across the machine.
__global__ __launch_bounds__(512) void qkv_gemm(
    const unsigned short* __restrict__ Qn, const unsigned short* __restrict__ X,
    const unsigned short* __restrict__ WtQ,
    const unsigned short* __restrict__ WtK, const unsigned short* __restrict__ WtV,
    const float* __restrict__ biasQ, const float* __restrict__ biasK,
    const float* __restrict__ biasV,
    unsigned short* __restrict__ qbf, unsigned short* __restrict__ kbf,
    unsigned short* __restrict__ vtbf) {
    __shared__ unsigned short sh[3 * 128 * GS_];
    int t = threadIdx.x, lane = t & 63, wv = t >> 6;
    int wm = wv >> 1, wn = wv & 1;
    int l15 = lane & 15, l4 = lane >> 4;
    int m0 = blockIdx.y * 128, n0 = blockIdx.x * 128;

    if (blockIdx.z == 0) {
        // ======== Q path (A = Qn, output qbf padded) ========
        unsigned short* As = sh;
        unsigned short* Ws = sh + 128 * GS_;
        f32x4 acc[2][4];
#pragma unroll
        for (int m = 0; m < 2; ++m)
#pragma unroll
            for (int n = 0; n < 4; ++n)
                acc[m][n] = f32x4{0.f, 0.f, 0.f, 0.f};

        for (int k0 = 0; k0 < D_; k0 += 64) {
#pragma unroll
            for (int rep = 0; rep < 2; ++rep) {
                int idx = rep * 512 + t;
                int r = idx >> 3, c8 = (idx & 7) * 8;
                *(i32x4*)&As[r * GS_ + c8] = *(const i32x4*)(Qn  + (size_t)(m0 + r) * D_ + k0 + c8);
                *(i32x4*)&Ws[r * GS_ + c8] = *(const i32x4*)(WtQ + (size_t)(n0 + r) * D_ + k0 + c8);
            }
            __syncthreads();
#pragma unroll
            for (int kk = 0; kk < 2; ++kk) {
                bf16x8 af[2], bf[4];
#pragma unroll
                for (int m = 0; m < 2; ++m)
                    af[m] = *(const bf16x8*)&As[(wm*32 + m*16 + l15) * GS_ + kk*32 + l4*8];
#pragma unroll
                for (int n = 0; n < 4; ++n)
                    bf[n] = *(const bf16x8*)&Ws[(wn*64 + n*16 + l15) * GS_ + kk*32 + l4*8];
#pragma unroll
                for (int m = 0; m < 2; ++m)
#pragma unroll
                    for (int n = 0; n < 4; ++n)
                        acc[m][n] = __builtin_amdgcn_mfma_f32_16x16x32_bf16(af[m], bf[n], acc[m][n], 0, 0, 0);
            }
            __syncthreads();
        }

        unsigned short* Ct = sh;
#pragma unroll
        for (int n = 0; n < 4; ++n) {
            int gnl = wn*64 + n*16 + l15;
            float bn = biasQ[n0 + gnl];
#pragma unroll
            for (int m = 0; m < 2; ++m)
#pragma unroll
                for (int i = 0; i < 4; ++i) {
                    int gml = wm*32 + m*16 + l4*4 + i;
                    Ct[gml * VS_ + gnl] = f2bf(acc[m][n][i] + bn);
                }
        }
        __syncthreads();
#pragma unroll
        for (int rep = 0; rep < 4; ++rep) {
            int idx = rep * 512 + t;
            int row = idx >> 4, c8 = (idx & 15) * 8;
            int gm = m0 + row, b = gm / 200, tt = gm - b * 200;
            *(i32x4*)&qbf[((size_t)b * TP_ + tt) * D_ + n0 + c8] =
                *(const i32x4*)&Ct[row * VS_ + c8];
        }
    } else {
        // ======== KV path (A = X, outputs kbf padded + vtbf transposed) ========
        unsigned short* As  = sh;
        unsigned short* WsK = sh + 128 * GS_;
        unsigned short* WsV = sh + 2 * 128 * GS_;
        f32x4 accK[2][4], accV[2][4];
#pragma unroll
        for (int m = 0; m < 2; ++m)
#pragma unroll
            for (int n = 0; n < 4; ++n) {
                accK[m][n] = f32x4{0.f, 0.f, 0.f, 0.f};
                accV[m][n] = f32x4{0.f, 0.f, 0.f, 0.f};
            }

        for (int k0 = 0; k0 < D_; k0 += 64) {
#pragma unroll
            for (int rep = 0; rep < 2; ++rep) {
                int idx = rep * 512 + t;
                int r = idx >> 3, c8 = (idx & 7) * 8;
                *(i32x4*)&As[r * GS_ + c8]  = *(const i32x4*)(X   + (size_t)(m0 + r) * D_ + k0 + c8);
                *(i32x4*)&WsK[r * GS_ + c8] = *(const i32x4*)(WtK + (size_t)(n0 + r) * D_ + k0 + c8);
                *(i32x4*)&WsV[r * GS_ + c8] = *(const i32x4*)(WtV + (size_t)(n0 + r) * D_ + k0 + c8);
            }
            __syncthreads();
#pragma unroll
            for (int kk = 0; kk < 2; ++kk) {
                bf16x8 af[2];
#pragma unroll
                for (int m = 0; m < 2; ++m)
                    af[m] = *(const bf16x8*)&As[(wm*32 + m*16 + l15) * GS_ + kk*32 + l4*8];
#pragma unroll
                for (int n = 0; n < 4; ++n) {
                    bf16x8 bk8 = *(const bf16x8*)&WsK[(wn*64 + n*16 + l15) * GS_ + kk*32 + l4*8];
                    bf16x8 bv8 = *(const bf16x8*)&WsV[(wn*64 + n*16 + l15) * GS_ + kk*32 + l4*8];
#pragma unroll
                    for (int m = 0; m < 2; ++m) {
                        accK[m][n] = __builtin_amdgcn_mfma_f32_16x16x32_bf16(af[m], bk8, accK[m][n], 0, 0, 0);
                        accV[m][n] = __builtin_amdgcn_mfma_f32_16x16x32_bf16(af[m], bv8, accV[m][n], 0, 0, 0);
                    }
                }
            }
            __syncthreads();
        }

        unsigned short* Ct = sh;
#pragma unroll
        for (int n = 0; n < 4; ++n) {
            int gnl = wn*64 + n*16 + l15;
            float bnK = biasK[n0 + gnl];
#pragma unroll
            for (int m = 0; m < 2; ++m)
#pragma unroll
                for (int i = 0; i < 4; ++i) {
                    int gml = wm*32 + m*16 + l4*4 + i;
                    Ct[gml * VS_ + gnl] = f2bf(accK[m][n][i] + bnK);
                }
        }
        __syncthreads();
#pragma unroll
        for (int rep = 0; rep < 4; ++rep) {
            int idx = rep * 512 + t;
            int row = idx >> 4, c8 = (idx & 15) * 8;
            int gm = m0 + row, b = gm / 200, tt = gm - b * 200;
            *(i32x4*)&kbf[((size_t)b * TP_ + tt) * D_ + n0 + c8] =
                *(const i32x4*)&Ct[row * VS_ + c8];
        }
        __syncthreads();

        unsigned short* Vt = sh;
#pragma unroll
        for (int n = 0; n < 4; ++n) {
            int gnl = wn*64 + n*16 + l15;
            float bnV = biasV[n0 + gnl];
#pragma unroll
            for (int m = 0; m < 2; ++m)
#pragma unroll
                for (int i = 0; i < 4; ++i) {
                    int gml = wm*32 + m*16 + l4*4 + i;
                    Vt[gnl * VS_ + gml] = f2bf(accV[m][n][i] + bnV);
                }
        }
        __syncthreads();
#pragma unroll
        for (int rep = 0; rep < 4; ++rep) {
            int idx = rep * 512 + t;
            int row = idx >> 4, c8 = (idx & 15) * 8;
            int gn = n0 + row, hh = gn >> 6, dk = gn & 63;
            int gm = m0 + c8, b = gm / 200, tt = gm - b * 200;
            *(i32x4*)&vtbf[(((size_t)b * H_ + hh) * 64 + dk) * VTP_ + tt] =
                *(const i32x4*)&Vt[row * VS_ + c8];
        }
    }
}

// ---------------- fused FFN: LN2 + relu(y@W1+b1)@W2 + b2 + y (32-row blocks) ---
__global__ __launch_bounds__(256) void ffn_fused(
    const unsigned short* __restrict__ S,
    const float* __restrict__ ln_s, const float* __restrict__ ln_b,
    const unsigned short* __restrict__ Wt1, const float* __restrict__ b1,
    const unsigned short* __restrict__ Wt2, const float* __restrict__ b2,
    unsigned short* __restrict__ OUT) {
    __shared__ unsigned short Alds[32 * FS_];
    __shared__ unsigned short Tlds[32 * FS_];
    __shared__ unsigned short Ws[256 * GS_];
    int t = threadIdx.x, lane = t & 63, wv = t >> 6;
    int l15 = lane & 15, l4 = lane >> 4;
    int m0 = blockIdx.x * 32;

    {
        int r = t >> 3, c = (t & 7) * 32;
        const unsigned short* src = S + (size_t)(m0 + r) * D_ + c;
        i32x4 buf[4];
#pragma unroll
        for (int j = 0; j < 4; ++j) buf[j] = ((const i32x4*)src)[j];
        float sum = 0.f;
#pragma unroll
        for (int j = 0; j < 4; ++j)
#pragma unroll
            for (int q = 0; q < 4; ++q)
                sum += bflo((unsigned)buf[j][q]) + bfhi((unsigned)buf[j][q]);
        sum += __shfl_xor(sum, 1);
        sum += __shfl_xor(sum, 2);
        sum += __shfl_xor(sum, 4);
        float mean = sum * (1.f / D_);
        float var = 0.f;
#pragma unroll
        for (int j = 0; j < 4; ++j)
#pragma unroll
            for (int q = 0; q < 4; ++q) {
                float a0 = bflo((unsigned)buf[j][q]) - mean;
                float a1 = bfhi((unsigned)buf[j][q]) - mean;
                var += a0*a0 + a1*a1;
            }
        var += __shfl_xor(var, 1);
        var += __shfl_xor(var, 2);
        var += __shfl_xor(var, 4);
        float inv = rsqrtf(var * (1.f / D_) + 1e-8f);
#pragma unroll
        for (int j = 0; j < 4; ++j) {
            int cc = c + j * 8;
            float4 sa = *(const float4*)&ln_s[cc];
            float4 sb = *(const float4*)&ln_s[cc + 4];
            float4 ba = *(const float4*)&ln_b[cc];
            float4 bb = *(const float4*)&ln_b[cc + 4];
            float y0 = (bflo((unsigned)buf[j][0]) - mean) * inv * sa.x + ba.x;
            float y1 = (bfhi((unsigned)buf[j][0]) - mean) * inv * sa.y + ba.y;
            float y2 = (bflo((unsigned)buf[j][1]) - mean) * inv * sa.z + ba.z;
            float y3 = (bfhi((unsigned)buf[j][1]) - mean) * inv * sa.w + ba.w;
            float y4 = (bflo((unsigned)buf[j][2]) - mean) * inv * sb.x + bb.x;
            float y5 = (bfhi((unsigned)buf[j][2]) - mean) * inv * sb.y + bb.y;
            float y6 = (bflo((unsigned)buf[j][3]) - mean) * inv * sb.z + bb.z;
            float y7 = (bfhi((unsigned)buf[j][3]) - mean) * inv * sb.w + bb.w;
            i32x4 w;
            w[0] = (int)pk2(y0, y1);
            w[1] = (int)pk2(y2, y3);
            w[2] = (int)pk2(y4, y5);
            w[3] = (int)pk2(y6, y7);
            *(i32x4*)&Alds[r * FS_ + cc] = w;
        }
    }
    __syncthreads();

    f32x4 acc[2][4];
#pragma unroll
    for (int m = 0; m < 2; ++m)
#pragma unroll
        for (int n = 0; n < 4; ++n)
            acc[m][n] = f32x4{0.f, 0.f, 0.f, 0.f};
    for (int k0 = 0; k0 < D_; k0 += 64) {
#pragma unroll
        for (int rep = 0; rep < 8; ++rep) {
            int idx = rep * 256 + t;
            int rr = idx >> 3, c8 = (idx & 7) * 8;
            *(i32x4*)&Ws[rr * GS_ + c8] = *(const i32x4*)(Wt1 + (size_t)rr * D_ + k0 + c8);
        }
        __syncthreads();
#pragma unroll
        for (int kk = 0; kk < 2; ++kk) {
            bf16x8 af[2], bf[4];
#pragma unroll
            for (int m = 0; m < 2; ++m)
                af[m] = *(const bf16x8*)&Alds[(m*16 + l15) * FS_ + k0 + kk*32 + l4*8];
#pragma unroll
            for (int n = 0; n < 4; ++n)
                bf[n] = *(const bf16x8*)&Ws[(wv*64 + n*16 + l15) * GS_ + kk*32 + l4*8];
#pragma unroll
            for (int m = 0; m < 2; ++m)
#pragma unroll
                for (int n = 0; n < 4; ++n)
                    acc[m][n] = __builtin_amdgcn_mfma_f32_16x16x32_bf16(af[m], bf[n], acc[m][n], 0, 0, 0);
        }
        __syncthreads();
    }
#pragma unroll
    for (int n = 0; n < 4; ++n) {
        int gn = wv*64 + n*16 + l15;
        float bn = b1[gn];
#pragma unroll
        for (int m = 0; m < 2; ++m)
#pragma unroll
            for (int i = 0; i < 4; ++i)
                Tlds[(m*16 + l4*4 + i) * FS_ + gn] = f2bf(fmaxf(acc[m][n][i] + bn, 0.f));
    }
    __syncthreads();

#pragma unroll
    for (int m = 0; m < 2; ++m)
#pragma unroll
        for (int n = 0; n < 4; ++n)
            acc[m][n] = f32x4{0.f, 0.f, 0.f, 0.f};
    for (int k0 = 0; k0 < D_; k0 += 64) {
#pragma unroll
        for (int rep = 0; rep < 8; ++rep) {
            int idx = rep * 256 + t;
            int rr = idx >> 3, c8 = (idx & 7) * 8;
            *(i32x4*)&Ws[rr * GS_ + c8] = *(const i32x4*)(Wt2 + (size_t)rr * D_ + k0 + c8);
        }
        __syncthreads();
#pragma unroll
        for (int kk = 0; kk < 2; ++kk) {
            bf16x8 af[2], bf[4];
#pragma unroll
            for (int m = 0; m < 2; ++m)
                af[m] = *(const bf16x8*)&Tlds[(m*16 + l15) * FS_ + k0 + kk*32 + l4*8];
#pragma unroll
            for (int n = 0; n < 4; ++n)
                bf[n] = *(const bf16x8*)&Ws[(wv*64 + n*16 + l15) * GS_ + kk*32 + l4*8];
#pragma unroll
            for (int m = 0; m < 2; ++m)
#pragma unroll
                for (int n = 0; n < 4; ++n)
                    acc[m][n] = __builtin_amdgcn_mfma_f32_16x16x32_bf16(af[m], bf[n], acc[m][n], 0, 0, 0);
        }
        __syncthreads();
    }
#pragma unroll
    for (int n = 0; n < 4; ++n) {
        int gn = wv*64 + n*16 + l15;
        float bn = b2[gn];
#pragma unroll
        for (int m = 0; m < 2; ++m) {
#pragma unroll
            for (int i = 0; i < 4; ++i) {
                int row = m*16 + l4*4 + i;
                float v = acc[m][n][i] + bn + bflo((unsigned)Alds[row * FS_ + gn]);
                Tlds[row * FS_ + gn] = f2bf(v);
            }
        }
    }
    __syncthreads();
#pragma unroll
    for (int rep = 0; rep < 4; ++rep) {
        int idx = rep * 256 + t;
        int row = idx >> 5, c8 = (idx & 31) * 8;
        *(i32x4*)&OUT[(size_t)(m0 + row) * D_ + c8] = *(const i32x4*)&Tlds[row * FS_ + c8];
    }
}

// ---------------- MFMA attention: round-19 form (best measured) ----------
// XCD-swizzled 1D grid (13312 = 8 x 1664); T5 setprio; float4 cm fetch;
// LDS-repacked coalesced O store.
template<bool DEC>
__global__ __launch_bounds__(64) void attn_mfma(
    const unsigned short* __restrict__ qbf,   // [b][208][256]
    const unsigned short* __restrict__ kbf,   // [b][208][256]
    const unsigned short* __restrict__ vtbf,  // [b*4+h][64][224]
    const float* __restrict__ cm,
    unsigned short* __restrict__ obf) {       // [bt][256]
    __shared__ unsigned short Olds[16 * 72];
    int o = ((blockIdx.x & 7) * 1664) + (blockIdx.x >> 3);
    int b = o / 52;
    int r = o - b * 52;
    int h = r / 13;
    int qt = r - h * 13;
    int lane = threadIdx.x;
    int l15 = lane & 15, l4 = lane >> 4;
    int q0 = qt * 16;
    int qr = q0 + l15;
    const f32x4 zero = {0.f, 0.f, 0.f, 0.f};

    size_t qkb = ((size_t)b * TP_) * D_ + h * 64;
    const unsigned short* qp = qbf + qkb + (size_t)(q0 + l15) * D_ + l4 * 8;
    bf16x8 bq0 = *(const bf16x8*)qp;
    bf16x8 bq1 = *(const bf16x8*)(qp + 32);

    // this lane's cm row (kk contiguous -> float4)
    const float* cmrow = DEC ? (cm + ((size_t)b * T_ + qr) * T_) : cm;

    size_t vbase = ((size_t)(b * H_ + h)) * 64 * VTP_;
    int sA = l15 + ((l4 & 1) << 5);
    int sB = sA + 16;
    bool lo4 = (l4 < 2);

    float m = -3e38f, l = 0.f;
    f32x4 O[4] = {zero, zero, zero, zero};

    int npair = (qt >> 1) + 1;
    for (int p = 0; p < npair; ++p) {
        int kt0 = 2 * p;
        bool hasOdd = (kt0 + 1 <= qt);

        f32x4 sv0, sv1;
        {
            const unsigned short* kp = kbf + qkb + (size_t)(kt0 * 16 + l15) * D_ + l4 * 8;
            bf16x8 ak0 = *(const bf16x8*)kp;
            bf16x8 ak1 = *(const bf16x8*)(kp + 32);
            __builtin_amdgcn_s_setprio(1);
            f32x4 acc = __builtin_amdgcn_mfma_f32_16x16x32_bf16(ak0, bq0, zero, 0, 0, 0);
            acc = __builtin_amdgcn_mfma_f32_16x16x32_bf16(ak1, bq1, acc, 0, 0, 0);
            __builtin_amdgcn_s_setprio(0);
            float cmarr[4] = {0.f, 0.f, 0.f, 0.f};
            if (DEC) {
                float4 cq = *(const float4*)&cmrow[kt0 * 16 + l4 * 4];
                cmarr[0] = cq.x; cmarr[1] = cq.y; cmarr[2] = cq.z; cmarr[3] = cq.w;
            }
#pragma unroll
            for (int i = 0; i < 4; ++i) {
                int kk = kt0 * 16 + l4 * 4 + i;
                float s = acc[i] * 0.125f;
                bool vld = (qr < T_) && (kk < T_);
                if (!vld) s = -1e9f;
                else {
                    if (kk > qr) s = -1e9f;   // mask BEFORE cm multiply (as reference)
                    if (DEC) s *= (1.0f + 0.5f * cmarr[i]);
                }
                sv0[i] = s;
            }
        }
        if (hasOdd) {
            const unsigned short* kp = kbf + qkb + (size_t)((kt0 + 1) * 16 + l15) * D_ + l4 * 8;
            bf16x8 ak0 = *(const bf16x8*)kp;
            bf16x8 ak1 = *(const bf16x8*)(kp + 32);
            __builtin_amdgcn_s_setprio(1);
            f32x4 acc = __builtin_amdgcn_mfma_f32_16x16x32_bf16(ak0, bq0, zero, 0, 0, 0);
            acc = __builtin_amdgcn_mfma_f32_16x16x32_bf16(ak1, bq1, acc, 0, 0, 0);
            __builtin_amdgcn_s_setprio(0);
            float cmarr[4] = {0.f, 0.f, 0.f, 0.f};
            if (DEC) {
                float4 cq = *(const float4*)&cmrow[(kt0 + 1) * 16 + l4 * 4];
                cmarr[0] = cq.x; cmarr[1] = cq.y; cmarr[2] = cq.z; cmarr[3] = cq.w;
            }
#pragma unroll
            for (int i = 0; i < 4; ++i) {
                int kk = (kt0 + 1) * 16 + l4 * 4 + i;
                float s = acc[i] * 0.125f;
                bool vld = (qr < T_) && (kk < T_);
                if (!vld) s = -1e9f;
                else {
                    if (kk > qr) s = -1e9f;
                    if (DEC) s *= (1.0f + 0.5f * cmarr[i]);
                }
                sv1[i] = s;
            }
        }

        float tm = fmaxf(fmaxf(sv0[0], sv0[1]), fmaxf(sv0[2], sv0[3]));
        if (hasOdd) {
            float tm1 = fmaxf(fmaxf(sv1[0], sv1[1]), fmaxf(sv1[2], sv1[3]));
            tm = fmaxf(tm, tm1);
        }
        tm = fmaxf(tm, __shfl_xor(tm, 16));
        tm = fmaxf(tm, __shfl_xor(tm, 32));
        float m_new = fmaxf(m, tm);
        float sc = __expf(m - m_new);
        m = m_new;
        l *= sc;
#pragma unroll
        for (int i = 0; i < 4; ++i) {
            float osc = __shfl(sc, l4 * 4 + i);
#pragma unroll
            for (int dt = 0; dt < 4; ++dt) O[dt][i] *= osc;
        }

        float p0[4], p1[4];
#pragma unroll
        for (int i = 0; i < 4; ++i) {
            p0[i] = __expf(sv0[i] - m);
            l += p0[i];
        }
        if (hasOdd) {
#pragma unroll
            for (int i = 0; i < 4; ++i) {
                p1[i] = __expf(sv1[i] - m);
                l += p1[i];
            }
        } else {
#pragma unroll
            for (int i = 0; i < 4; ++i) p1[i] = 0.f;
        }

        unsigned pk0a = pk2(p0[0], p0[1]), pk0b = pk2(p0[2], p0[3]);
        unsigned pk1a = pk2(p1[0], p1[1]), pk1b = pk2(p1[2], p1[3]);
        unsigned e0 = (unsigned)__shfl((int)pk0a, sA);
        unsigned e1 = (unsigned)__shfl((int)pk0b, sA);
        unsigned e2 = (unsigned)__shfl((int)pk0a, sB);
        unsigned e3 = (unsigned)__shfl((int)pk0b, sB);
        unsigned o0 = (unsigned)__shfl((int)pk1a, sA);
        unsigned o1 = (unsigned)__shfl((int)pk1b, sA);
        unsigned o2 = (unsigned)__shfl((int)pk1a, sB);
        unsigned o3 = (unsigned)__shfl((int)pk1b, sB);
        frag8 pa;
        pa.u[0] = lo4 ? e0 : o0;
        pa.u[1] = lo4 ? e1 : o1;
        pa.u[2] = lo4 ? e2 : o2;
        pa.u[3] = lo4 ? e3 : o3;

        __builtin_amdgcn_s_setprio(1);
#pragma unroll
        for (int dt = 0; dt < 4; ++dt) {
            bf16x8 vf = *(const bf16x8*)&vtbf[vbase + (size_t)(dt * 16 + l15) * VTP_ + p * 32 + l4 * 8];
            O[dt] = __builtin_amdgcn_mfma_f32_16x16x32_bf16(pa.v, vf, O[dt], 0, 0, 0);
        }
        __builtin_amdgcn_s_setprio(0);
    }

    float L = l;
    L += __shfl_xor(L, 16);
    L += __shfl_xor(L, 32);
    float inv = 1.f / L;
#pragma unroll
    for (int i = 0; i < 4; ++i) {
        float oin = __shfl(inv, l4 * 4 + i);
#pragma unroll
        for (int dt = 0; dt < 4; ++dt)
            Olds[(l4 * 4 + i) * 72 + dt * 16 + l15] = f2bf(O[dt][i] * oin);
    }
    __syncthreads();
#pragma unroll
    for (int rep = 0; rep < 2; ++rep) {
        int idx = rep * 64 + lane;
        int row = idx >> 3, c8 = (idx & 7) * 8;
        int qrow = q0 + row;
        if (qrow < T_)
            *(i32x4*)&obf[((size_t)(b * T_) + qrow) * D_ + h * 64 + c8] =
                *(const i32x4*)&Olds[row * 72 + c8];
    }
}

// ---------------- cov (bf16 Z in; row mean computed inline per wave) ----------------
__global__ __launch_bounds__(512) void cov_mfma(const unsigned short* __restrict__ Z,
                                                float* __restrict__ cm) {
    __shared__ unsigned short Zb[208 * ZS_];
    int b = blockIdx.x;
    int tid = threadIdx.x, lane = tid & 63, wv = tid >> 6;
    int l15 = lane & 15, l4 = lane >> 4;

    for (int i = tid; i < T_ * 64; i += 512) {
        int t = i >> 6, c4 = (i & 63) << 2;
        i32x2 z = *(const i32x2*)(Z + ((size_t)b * T_ + t) * D_ + c4);
        float z0 = bflo((unsigned)z[0]), z1 = bfhi((unsigned)z[0]);
        float z2 = bflo((unsigned)z[1]), z3 = bfhi((unsigned)z[1]);
        float mean = wave_sum(z0 + z1 + z2 + z3) * (1.f / D_);
        unsigned* p = (unsigned*)&Zb[t * ZS_ + c4];
        p[0] = pk2(z0 - mean, z1 - mean);
        p[1] = pk2(z2 - mean, z3 - mean);
    }
    for (int i = tid; i < 8 * ZS_; i += 512) Zb[T_ * ZS_ + i] = 0;
    __syncthreads();

    for (int job = wv; job < 91; job += 8) {
        int ti = 0;
        while ((ti + 1) * (ti + 2) / 2 <= job) ++ti;
        int tj = job - ti * (ti + 1) / 2;
        f32x4 acc = {0.f, 0.f, 0.f, 0.f};
#pragma unroll
        for (int s = 0; s < 8; ++s) {
            bf16x8 a  = *(const bf16x8*)&Zb[(ti * 16 + l15) * ZS_ + s * 32 + l4 * 8];
            bf16x8 bb = *(const bf16x8*)&Zb[(tj * 16 + l15) * ZS_ + s * 32 + l4 * 8];
            acc = __builtin_amdgcn_mfma_f32_16x16x32_bf16(a, bb, acc, 0, 0, 0);
        }
#pragma unroll
        for (int i = 0; i < 4; ++i) {
            int t = ti * 16 + l4 * 4 + i, s2 = tj * 16 + l15;
            float vv = fminf(acc[i] * (1.f / 255.f), 3.0f);
            if (t < T_ && s2 < T_) {
                cm[((size_t)b * T_ + t) * T_ + s2] = vv;
                cm[((size_t)b * T_ + s2) * T_ + t] = vv;
            }
        }
    }
}

extern "C" void kernel_launch(void* const* d_in, const int* in_sizes, int n_in,
                              void* d_out, int out_size, void* d_ws, size_t ws_size,
                              hipStream_t stream) {
    const int*   log_seqs = (const int*)  d_in[0];
    const float* item_tab = (const float*)d_in[1];
    const float* pos_tab  = (const float*)d_in[2];
    const float* ln1_s = (const float*)d_in[3];
    const float* ln1_b = (const float*)d_in[4];
    const float* Wq = (const float*)d_in[5];
    const float* bq = (const float*)d_in[6];
    const float* Wk = (const float*)d_in[7];
    const float* bk = (const float*)d_in[8];
    const float* Wv = (const float*)d_in[9];
    const float* bv = (const float*)d_in[10];
    const float* Wo = (const float*)d_in[11];
    const float* bo = (const float*)d_in[12];
    const float* ln2_s = (const float*)d_in[13];
    const float* ln2_b = (const float*)d_in[14];
    const float* W1 = (const float*)d_in[15];
    const float* b1 = (const float*)d_in[16];
    const float* W2 = (const float*)d_in[17];
    const float* b2 = (const float*)d_in[18];
    const float* last_s = (const float*)d_in[19];
    const float* last_b = (const float*)d_in[20];

    const size_t NTD = (size_t)BT_ * D_;
    float* cmask = (float*)d_ws;                               // B*T*T fp32
    unsigned short* act = (unsigned short*)(cmask + (size_t)B_ * T_ * T_);
    unsigned short* s0   = act;              // seqs / layer-3 out
    unsigned short* s1   = s0 + NTD;         // causal_z / layer-2 out
    unsigned short* Qn   = s1 + NTD;         // ln1 out, then s (in-place)
    unsigned short* vb   = Qn + NTD;         // obf
    unsigned short* qbf  = vb + NTD;                         // [B][208][256]
    unsigned short* kbf  = qbf + (size_t)B_ * TP_ * D_;      // [B][208][256]
    unsigned short* vtbf = kbf + (size_t)B_ * TP_ * D_;      // [B*H][64][224]
    unsigned short* wtb  = vtbf + (size_t)B_ * H_ * 64 * VTP_;

    unsigned short* wtq = wtb;
    unsigned short* wtk = wtb + 4 * (size_t)DD_;
    unsigned short* wtv = wtb + 8 * (size_t)DD_;
    unsigned short* wto = wtb + 12 * (size_t)DD_;
    unsigned short* wt1 = wtb + 16 * (size_t)DD_;
    unsigned short* wt2 = wtb + 20 * (size_t)DD_;

    // transpose only layers 1..3 (layer 0 unused: causal loop keeps only layer 1)
    dim3 tg(4, 4, 3);
    wtrans_kernel<<<tg, 256, 0, stream>>>(Wq + DD_, wtq + DD_);
    wtrans_kernel<<<tg, 256, 0, stream>>>(Wk + DD_, wtk + DD_);
    wtrans_kernel<<<tg, 256, 0, stream>>>(Wv + DD_, wtv + DD_);
    wtrans_kernel<<<tg, 256, 0, stream>>>(Wo + DD_, wto + DD_);
    wtrans_kernel<<<tg, 256, 0, stream>>>(W1 + DD_, wt1 + DD_);
    wtrans_kernel<<<tg, 256, 0, stream>>>(W2 + DD_, wt2 + DD_);
    vtpad_kernel<<<B_ * H_ * 64, 32, 0, stream>>>(vtbf);

    dim3 gg(2, 400);        // N/128, M/128 (Wo gemm)
    dim3 gq(2, 400, 2);     // merged QKV: z=0 Q, z=1 KV

    auto encoder = [&](const unsigned short* X, unsigned short* OUT, int i, const float* cmp) {
        ln_kernel<false><<<BT_/4, 256, 0, stream>>>(X, ln1_s + i*D_, ln1_b + i*D_, Qn);
        qkv_gemm<<<gq, 512, 0, stream>>>(Qn, X,
                                         wtq + (size_t)i*DD_, wtk + (size_t)i*DD_, wtv + (size_t)i*DD_,
                                         bq + i*D_, bk + i*D_, bv + i*D_,
                                         qbf, kbf, vtbf);
        if (cmp) attn_mfma<true ><<<13312, 64, 0, stream>>>(qbf, kbf, vtbf, cmp, vb);
        else     attn_mfma<false><<<13312, 64, 0, stream>>>(qbf, kbf, vtbf, nullptr, vb);
        // s = Qn + vb @ Wo + bo  (in-place into Qn; element-exclusive)
        gemm_mfma<0,true><<<gg, 512, 0, stream>>>(vb, wto + (size_t)i*DD_, bo + i*D_, Qn, Qn);
        // OUT = relu(LN2(s)@W1+b1)@W2 + b2 + LN2(s)
        ffn_fused<<<BT_/32, 256, 0, stream>>>(Qn, ln2_s + i*D_, ln2_b + i*D_,
                                              wt1 + (size_t)i*DD_, b1 + i*D_,
                                              wt2 + (size_t)i*DD_, b2 + i*D_, OUT);
    };

    embed_kernel<<<BT_, 64, 0, stream>>>(log_seqs, item_tab, pos_tab, s0);

    // causal loop applies each layer to ORIGINAL seqs -> only layer 1 survives
    encoder(s0, s1, 1, nullptr);

    cov_mfma<<<B_, 512, 0, stream>>>(s1, cmask);

    encoder(s0, s1, 2, cmask);
    encoder(s1, s0, 3, cmask);

    ln_kernel<true><<<BT_/4, 256, 0, stream>>>(s0, last_s, last_b, (float*)d_out);
}